// Round 1
// baseline (2327.929 us; speedup 1.0000x reference)
//
#include <hip/hip_runtime.h>

// BilinearAttention: B=8, N=2048, H=1024
//   inter = Q @ W                  (B*N, H) x (H, H)          fp32
//   e     = relu(inter @ V^T)      per-batch (N,H) x (N,H)^T  fp32
//   logit = mask>0 ? e : -1e9
//   attn  = softmax(logit, axis=-1)        -> d_out[B*N*H ..]
//   out   = attn @ V               per-batch (N,N) x (N,H)    -> d_out[0 ..]
//
// inter is staged in the d_out "output" region (same size B*N*H) and is fully
// consumed by GEMM2 before GEMM3 overwrites that region. No d_ws used.

#define BATCH 8
#define SEQ   2048
#define HID   1024
#define MINV  (-1e9f)

// ---------------------------------------------------------------------------
// Generic fp32 SGEMM, 128x128 tile, BK=8, 256 threads, 8x8 per-thread tile.
// BT:  B operand is transposed (C[m][n] = sum_k A[m][k] * B[n][k])
// EPI: fused relu + mask epilogue (GEMM2)
// lda == K, ldb == (BT ? K : N), ldc == N  -- true for all three GEMMs here.
// ---------------------------------------------------------------------------
template <bool BT, bool EPI>
__global__ __launch_bounds__(256) void gemm128(
    const float* __restrict__ Abase, const float* __restrict__ Bbase,
    float* __restrict__ Cbase, const int* __restrict__ Mbase,
    int M, int N, int K, long sA, long sB, long sC, long sM)
{
    const int b = blockIdx.z;
    const float* A = Abase + (long)b * sA;
    const float* Bm = Bbase + (long)b * sB;
    float* C = Cbase + (long)b * sC;
    const int* Mk = EPI ? (Mbase + (long)b * sM) : nullptr;

    __shared__ float As[8][128];
    __shared__ float Bs[8][128];

    const int tid = threadIdx.x;
    const int m0 = blockIdx.y * 128;
    const int n0 = blockIdx.x * 128;
    const int r0 = (tid >> 4) * 8;   // row offset of this thread's 8x8 tile
    const int c0 = (tid & 15) * 8;   // col offset

    float acc[8][8] = {};

    // staging indices
    const int lr = tid >> 1;         // 0..127 : row (A) / row (B^T)
    const int lk = (tid & 1) * 4;    // 0 or 4 : k quad
    const int bk = tid >> 5;         // 0..7   : k row (B normal)
    const int bn = (tid & 31) * 4;   // 0..124 : n quad (B normal)

    for (int k0 = 0; k0 < K; k0 += 8) {
        float4 av = *(const float4*)(A + (long)(m0 + lr) * K + k0 + lk);
        float4 bv;
        if (BT) {
            bv = *(const float4*)(Bm + (long)(n0 + lr) * K + k0 + lk);
        } else {
            bv = *(const float4*)(Bm + (long)(k0 + bk) * N + n0 + bn);
        }
        __syncthreads();   // previous iteration's compute done before overwrite
        As[lk + 0][lr] = av.x; As[lk + 1][lr] = av.y;
        As[lk + 2][lr] = av.z; As[lk + 3][lr] = av.w;
        if (BT) {
            Bs[lk + 0][lr] = bv.x; Bs[lk + 1][lr] = bv.y;
            Bs[lk + 2][lr] = bv.z; Bs[lk + 3][lr] = bv.w;
        } else {
            *(float4*)&Bs[bk][bn] = bv;
        }
        __syncthreads();
#pragma unroll
        for (int kk = 0; kk < 8; ++kk) {
            float a[8], bb[8];
            *(float4*)&a[0] = *(const float4*)&As[kk][r0];
            *(float4*)&a[4] = *(const float4*)&As[kk][r0 + 4];
            *(float4*)&bb[0] = *(const float4*)&Bs[kk][c0];
            *(float4*)&bb[4] = *(const float4*)&Bs[kk][c0 + 4];
#pragma unroll
            for (int i = 0; i < 8; ++i)
#pragma unroll
                for (int j = 0; j < 8; ++j)
                    acc[i][j] = fmaf(a[i], bb[j], acc[i][j]);
        }
    }

#pragma unroll
    for (int i = 0; i < 8; ++i) {
        const int row = m0 + r0 + i;
        const long off = (long)row * N + n0 + c0;
        if (EPI) {
            int4 mm0 = *(const int4*)(Mk + off);
            int4 mm1 = *(const int4*)(Mk + off + 4);
            float v[8];
            const int mi[8] = {mm0.x, mm0.y, mm0.z, mm0.w,
                               mm1.x, mm1.y, mm1.z, mm1.w};
#pragma unroll
            for (int j = 0; j < 8; ++j) {
                float e = acc[i][j] > 0.f ? acc[i][j] : 0.f;
                v[j] = (mi[j] > 0) ? e : MINV;
            }
            *(float4*)(C + off) = make_float4(v[0], v[1], v[2], v[3]);
            *(float4*)(C + off + 4) = make_float4(v[4], v[5], v[6], v[7]);
        } else {
            *(float4*)(C + off) =
                make_float4(acc[i][0], acc[i][1], acc[i][2], acc[i][3]);
            *(float4*)(C + off + 4) =
                make_float4(acc[i][4], acc[i][5], acc[i][6], acc[i][7]);
        }
    }
}

// ---------------------------------------------------------------------------
// Row softmax over 2048 elements, in place. One block (256 thr) per row.
// Masked entries are -1e9: exp underflows to 0. All-masked row -> uniform,
// matching the reference (exp(0)=1 for every entry).
// ---------------------------------------------------------------------------
__global__ __launch_bounds__(256) void softmax2048(float* __restrict__ attn)
{
    const long row = blockIdx.x;
    float* p = attn + row * 2048;
    const int tid = threadIdx.x;

    float4 v0 = ((const float4*)p)[tid];
    float4 v1 = ((const float4*)p)[tid + 256];

    float mx = fmaxf(fmaxf(fmaxf(v0.x, v0.y), fmaxf(v0.z, v0.w)),
                     fmaxf(fmaxf(v1.x, v1.y), fmaxf(v1.z, v1.w)));
#pragma unroll
    for (int o = 32; o >= 1; o >>= 1)
        mx = fmaxf(mx, __shfl_xor(mx, o, 64));

    __shared__ float redm[4];
    __shared__ float reds[4];
    const int wid = tid >> 6, lane = tid & 63;
    if (lane == 0) redm[wid] = mx;
    __syncthreads();
    mx = fmaxf(fmaxf(redm[0], redm[1]), fmaxf(redm[2], redm[3]));

    float e[8];
    e[0] = __expf(v0.x - mx); e[1] = __expf(v0.y - mx);
    e[2] = __expf(v0.z - mx); e[3] = __expf(v0.w - mx);
    e[4] = __expf(v1.x - mx); e[5] = __expf(v1.y - mx);
    e[6] = __expf(v1.z - mx); e[7] = __expf(v1.w - mx);

    float s = ((e[0] + e[1]) + (e[2] + e[3])) + ((e[4] + e[5]) + (e[6] + e[7]));
#pragma unroll
    for (int o = 32; o >= 1; o >>= 1)
        s += __shfl_xor(s, o, 64);
    if (lane == 0) reds[wid] = s;
    __syncthreads();
    s = (reds[0] + reds[1]) + (reds[2] + reds[3]);

    const float inv = 1.0f / s;
    ((float4*)p)[tid]       = make_float4(e[0] * inv, e[1] * inv, e[2] * inv, e[3] * inv);
    ((float4*)p)[tid + 256] = make_float4(e[4] * inv, e[5] * inv, e[6] * inv, e[7] * inv);
}

extern "C" void kernel_launch(void* const* d_in, const int* in_sizes, int n_in,
                              void* d_out, int out_size, void* d_ws, size_t ws_size,
                              hipStream_t stream)
{
    (void)in_sizes; (void)n_in; (void)out_size; (void)d_ws; (void)ws_size;

    const float* query = (const float*)d_in[0];  // B,N,H
    const float* value = (const float*)d_in[1];  // B,N,H
    const int*   mask  = (const int*)d_in[2];    // B,N,N
    const float* W     = (const float*)d_in[3];  // H,H

    float* out  = (float*)d_out;                       // B*N*H
    float* attn = out + (long)BATCH * SEQ * HID;       // B*N*N
    float* inter = out;  // stage inter in output region (consumed before GEMM3)

    const dim3 blk(256);

    // GEMM1: inter[B*N, H] = query[B*N, H] @ W[H, H]   (NN, batch folded)
    gemm128<false, false><<<dim3(HID / 128, (BATCH * SEQ) / 128, 1), blk, 0, stream>>>(
        query, W, inter, nullptr, BATCH * SEQ, HID, HID, 0, 0, 0, 0);

    // GEMM2: logits[b][N,N] = relu(inter_b @ V_b^T) masked  (NT + epilogue)
    gemm128<true, true><<<dim3(SEQ / 128, SEQ / 128, BATCH), blk, 0, stream>>>(
        inter, value, attn, mask, SEQ, SEQ, HID,
        (long)SEQ * HID, (long)SEQ * HID, (long)SEQ * SEQ, (long)SEQ * SEQ);

    // softmax rows (in place in d_out attn region)
    softmax2048<<<dim3(BATCH * SEQ), blk, 0, stream>>>(attn);

    // GEMM3: out_b[N, H] = attn_b[N, N] @ V_b[N, H]   (NN)
    gemm128<false, false><<<dim3(HID / 128, SEQ / 128, BATCH), blk, 0, stream>>>(
        attn, value, out, nullptr, SEQ, HID, SEQ,
        (long)SEQ * SEQ, (long)SEQ * HID, (long)SEQ * HID, 0);
}

// Round 2
// 1009.197 us; speedup vs baseline: 2.3067x; 2.3067x over previous
//
#include <hip/hip_runtime.h>

// BilinearAttention B=8, N=2048, H=1024 — MFMA f16-split pipeline.
//   prep_v : value fp32 -> Vp packed(hi|lo u32)[b][n][h]  +  Vt f16 [b][h][n]
//   prep_w : W fp32 [k][n] -> Wtp packed [n][k]
//   gemm<1>: interP[m][k-packed] = split(Q) @ Wtp   (3-MFMA split, fp32->hi/lo on the fly)
//            -> written packed into d_out "output" region (consumed by gemm<2>)
//   gemm<2>: attn-logits = relu(interP @ Vp^T) masked  (split, packed operands)
//   softmax: rowwise, in place
//   gemm<3>: out = attn @ V  (plain f16 MFMA, B from Vt so k is contiguous)

typedef _Float16 half8 __attribute__((ext_vector_type(8)));
typedef float f32x4 __attribute__((ext_vector_type(4)));
typedef unsigned short u16;
typedef unsigned int u32;

#define BATCH 8
#define SEQ   2048
#define HID   1024
#define MINV  (-1e9f)
#define BK    32
#define RS    40      // LDS row stride in halfs (pad 32 -> 40: 2-way bank aliasing, free)

__device__ __forceinline__ u16 h2u(_Float16 h) { return __builtin_bit_cast(u16, h); }

// split fp32 -> (hi,lo) f16 packed into one u32 (hi in low half)
__device__ __forceinline__ u32 packhl(float x) {
    _Float16 h = (_Float16)x;
    _Float16 l = (_Float16)(x - (float)h);
    return (u32)h2u(h) | ((u32)h2u(l) << 16);
}

// fp32x4 -> hi-pair/lo-pair (4 halfs each, as uint2)
__device__ __forceinline__ void split4(const float4 x, uint2& hv, uint2& lv) {
    u32 p0 = packhl(x.x), p1 = packhl(x.y), p2 = packhl(x.z), p3 = packhl(x.w);
    hv.x = (p0 & 0xffffu) | (p1 << 16);
    hv.y = (p2 & 0xffffu) | (p3 << 16);
    lv.x = (p0 >> 16) | (p1 & 0xffff0000u);
    lv.y = (p2 >> 16) | (p3 & 0xffff0000u);
}

// packed u32x4 -> hi-pair/lo-pair
__device__ __forceinline__ void unpack4(const uint4 p, uint2& hv, uint2& lv) {
    hv.x = (p.x & 0xffffu) | (p.y << 16);
    hv.y = (p.z & 0xffffu) | (p.w << 16);
    lv.x = (p.x >> 16) | (p.y & 0xffff0000u);
    lv.y = (p.z >> 16) | (p.w & 0xffff0000u);
}

// fp32x4 -> 4 halfs (plain cvt)
__device__ __forceinline__ void cvt4(const float4 x, uint2& hv) {
    hv.x = (u32)h2u((_Float16)x.x) | ((u32)h2u((_Float16)x.y) << 16);
    hv.y = (u32)h2u((_Float16)x.z) | ((u32)h2u((_Float16)x.w) << 16);
}

// ---------------------------------------------------------------------------
// prep_v: 64x64 tiles. Writes Vp (packed, same layout) coalesced and Vt
// (f16, transposed to [b][h][n]) via LDS transpose.
// ---------------------------------------------------------------------------
__global__ __launch_bounds__(256) void prep_v(const float* __restrict__ V,
                                              u32* __restrict__ Vp,
                                              u16* __restrict__ Vt)
{
    __shared__ __align__(16) u16 lt[64 * 72];
    const int b = blockIdx.z, n0 = blockIdx.y * 64, h0 = blockIdx.x * 64;
    const int t = threadIdx.x;
    const int r = t >> 4, c4 = (t & 15) * 4;
#pragma unroll
    for (int it = 0; it < 4; ++it) {
        const int rr = r + it * 16;
        const float4 x = *(const float4*)(V + ((size_t)b * SEQ + n0 + rr) * HID + h0 + c4);
        const float xs[4] = {x.x, x.y, x.z, x.w};
        u32 p[4];
#pragma unroll
        for (int e = 0; e < 4; ++e) {
            _Float16 h = (_Float16)xs[e];
            _Float16 l = (_Float16)(xs[e] - (float)h);
            p[e] = (u32)h2u(h) | ((u32)h2u(l) << 16);
            lt[(c4 + e) * 72 + rr] = h2u(h);
        }
        *(uint4*)(Vp + ((size_t)b * SEQ + n0 + rr) * HID + h0 + c4) =
            make_uint4(p[0], p[1], p[2], p[3]);
    }
    __syncthreads();
    const int hr = t >> 2, cc = (t & 3) * 2;
    uint4 v0 = *(const uint4*)&lt[hr * 72 + cc * 8];
    uint4 v1 = *(const uint4*)&lt[hr * 72 + cc * 8 + 8];
    u16* dst = Vt + ((size_t)b * HID + h0 + hr) * SEQ + n0 + cc * 8;
    *(uint4*)dst = v0;
    *(uint4*)(dst + 8) = v1;
}

// ---------------------------------------------------------------------------
// prep_w: W [k][n] fp32 -> Wtp [n][k] packed hi/lo u32, 64x64 LDS transpose.
// ---------------------------------------------------------------------------
__global__ __launch_bounds__(256) void prep_w(const float* __restrict__ W,
                                              u32* __restrict__ Wtp)
{
    __shared__ __align__(16) u32 lt[64 * 68];
    const int n0 = blockIdx.x * 64, k0 = blockIdx.y * 64;
    const int t = threadIdx.x;
    const int r = t >> 4, c4 = (t & 15) * 4;
#pragma unroll
    for (int it = 0; it < 4; ++it) {
        const int rr = r + it * 16;
        const float4 x = *(const float4*)(W + (size_t)(k0 + rr) * HID + n0 + c4);
        const float xs[4] = {x.x, x.y, x.z, x.w};
#pragma unroll
        for (int e = 0; e < 4; ++e) lt[(c4 + e) * 68 + rr] = packhl(xs[e]);
    }
    __syncthreads();
    const int n = t >> 2;
#pragma unroll
    for (int s = 0; s < 4; ++s) {
        const int ci = (t & 3) + s * 4;
        uint4 v = *(const uint4*)&lt[n * 68 + ci * 4];
        *(uint4*)(Wtp + (size_t)(n0 + n) * HID + k0 + ci * 4) = v;
    }
}

// ---------------------------------------------------------------------------
// MFMA GEMM, 128x128 block tile, BK=32, 4 waves (each 64x64 = 4x4 MFMA tiles).
// MODE 1: A fp32 (split on the fly), B packed, C packed-u32 out      [gemm1]
// MODE 2: A packed, B packed, relu+mask epilogue, C fp32             [gemm2]
// MODE 3: A fp32 (plain f16 cvt), B f16 (direct copy), C fp32        [gemm3]
// A_lds/B_lds layout: [row][k] halfs, row stride RS=40.
// MFMA 16x16x32_f16 fragments: A/B lane: row/col = lane&15, k = (lane>>4)*8+j.
// C/D: col = lane&15, row = (lane>>4)*4 + reg.
// ---------------------------------------------------------------------------
template <int MODE>
__global__ __launch_bounds__(256) void gemm_mfma(
    const void* __restrict__ Abase, const void* __restrict__ Bbase,
    void* __restrict__ Cbase, const int* __restrict__ Mbase,
    int M, int N, int K, int lda, int ldb, int ldc,
    long sA, long sB, long sC, long sM)
{
    constexpr bool SPLIT = (MODE != 3);
    const int b = blockIdx.z;
    const int tid = threadIdx.x;
    const int m0 = blockIdx.y * 128, n0 = blockIdx.x * 128;

    __shared__ __align__(16) u16 smem[(SPLIT ? 4 : 2) * 128 * RS];
    u16* Ah = smem;
    u16* Al = smem + 128 * RS;                       // split only
    u16* Bh = smem + (SPLIT ? 2 : 1) * 128 * RS;
    u16* Bl = smem + 3 * 128 * RS;                   // split only

    const int srow = tid >> 1;            // staging row 0..127
    const int skb = (tid & 1) * 16;       // staging k base 0/16

    const int w = tid >> 6, lane = tid & 63;
    const int wr = (w >> 1) * 64, wc = (w & 1) * 64;
    const int lm = lane & 15, q = lane >> 4;

    f32x4 acc[4][4];
#pragma unroll
    for (int i = 0; i < 4; ++i)
#pragma unroll
        for (int j = 0; j < 4; ++j) acc[i][j] = (f32x4){0.f, 0.f, 0.f, 0.f};

    for (int k0 = 0; k0 < K; k0 += BK) {
        uint2 AH[4], AL[4], BH[4], BL[4];
        uint4 bcopy[2];
        // ---- global loads ----
        if constexpr (MODE == 2) {
            const u32* Ap = (const u32*)Abase + (long)b * sA + (long)(m0 + srow) * lda + k0 + skb;
#pragma unroll
            for (int c = 0; c < 4; ++c) unpack4(*(const uint4*)(Ap + 4 * c), AH[c], AL[c]);
        } else {
            const float* Af = (const float*)Abase + (long)b * sA + (long)(m0 + srow) * lda + k0 + skb;
#pragma unroll
            for (int c = 0; c < 4; ++c) {
                float4 x = *(const float4*)(Af + 4 * c);
                if constexpr (MODE == 1) split4(x, AH[c], AL[c]);
                else cvt4(x, AH[c]);
            }
        }
        if constexpr (MODE <= 2) {
            const u32* Bp = (const u32*)Bbase + (long)b * sB + (long)(n0 + srow) * ldb + k0 + skb;
#pragma unroll
            for (int c = 0; c < 4; ++c) unpack4(*(const uint4*)(Bp + 4 * c), BH[c], BL[c]);
        } else {
            const u16* Bf = (const u16*)Bbase + (long)b * sB + (long)(n0 + srow) * ldb + k0 + skb;
            bcopy[0] = ((const uint4*)Bf)[0];
            bcopy[1] = ((const uint4*)Bf)[1];
        }
        __syncthreads();
        // ---- LDS stores ----
#pragma unroll
        for (int c = 0; c < 4; ++c) {
            *(uint2*)&Ah[srow * RS + skb + 4 * c] = AH[c];
            if constexpr (SPLIT) *(uint2*)&Al[srow * RS + skb + 4 * c] = AL[c];
        }
        if constexpr (MODE <= 2) {
#pragma unroll
            for (int c = 0; c < 4; ++c) {
                *(uint2*)&Bh[srow * RS + skb + 4 * c] = BH[c];
                *(uint2*)&Bl[srow * RS + skb + 4 * c] = BL[c];
            }
        } else {
            *(uint4*)&Bh[srow * RS + skb] = bcopy[0];
            *(uint4*)&Bh[srow * RS + skb + 8] = bcopy[1];
        }
        __syncthreads();
        // ---- MFMA ----
        half8 af[4], alf[4];
#pragma unroll
        for (int i = 0; i < 4; ++i) {
            const int ro = (wr + i * 16 + lm) * RS + q * 8;
            af[i] = *(const half8*)&Ah[ro];
            if constexpr (SPLIT) alf[i] = *(const half8*)&Al[ro];
        }
#pragma unroll
        for (int j = 0; j < 4; ++j) {
            const int co = (wc + j * 16 + lm) * RS + q * 8;
            half8 bf = *(const half8*)&Bh[co];
            half8 blf;
            if constexpr (SPLIT) blf = *(const half8*)&Bl[co];
#pragma unroll
            for (int i = 0; i < 4; ++i) {
                if constexpr (SPLIT) {
                    acc[i][j] = __builtin_amdgcn_mfma_f32_16x16x32_f16(alf[i], bf, acc[i][j], 0, 0, 0);
                    acc[i][j] = __builtin_amdgcn_mfma_f32_16x16x32_f16(af[i], blf, acc[i][j], 0, 0, 0);
                }
                acc[i][j] = __builtin_amdgcn_mfma_f32_16x16x32_f16(af[i], bf, acc[i][j], 0, 0, 0);
            }
        }
    }

    // ---- epilogue ----
#pragma unroll
    for (int i = 0; i < 4; ++i) {
#pragma unroll
        for (int r = 0; r < 4; ++r) {
            const int grow = m0 + wr + i * 16 + q * 4 + r;
#pragma unroll
            for (int j = 0; j < 4; ++j) {
                const int gcol = n0 + wc + j * 16 + lm;
                const float v = acc[i][j][r];
                if constexpr (MODE == 1) {
                    ((u32*)Cbase)[(long)grow * ldc + gcol] = packhl(v);
                } else if constexpr (MODE == 2) {
                    const int mv = Mbase[(long)b * sM + (long)grow * ldc + gcol];
                    ((float*)Cbase)[(long)b * sC + (long)grow * ldc + gcol] =
                        (mv > 0) ? fmaxf(v, 0.f) : MINV;
                } else {
                    ((float*)Cbase)[(long)b * sC + (long)grow * ldc + gcol] = v;
                }
            }
        }
    }
}

// ---------------------------------------------------------------------------
// Row softmax over 2048 elements, in place. One block (256 thr) per row.
// ---------------------------------------------------------------------------
__global__ __launch_bounds__(256) void softmax2048(float* __restrict__ attn)
{
    const long row = blockIdx.x;
    float* p = attn + row * 2048;
    const int tid = threadIdx.x;

    float4 v0 = ((const float4*)p)[tid];
    float4 v1 = ((const float4*)p)[tid + 256];

    float mx = fmaxf(fmaxf(fmaxf(v0.x, v0.y), fmaxf(v0.z, v0.w)),
                     fmaxf(fmaxf(v1.x, v1.y), fmaxf(v1.z, v1.w)));
#pragma unroll
    for (int o = 32; o >= 1; o >>= 1)
        mx = fmaxf(mx, __shfl_xor(mx, o, 64));

    __shared__ float redm[4];
    __shared__ float reds[4];
    const int wid = tid >> 6, lane = tid & 63;
    if (lane == 0) redm[wid] = mx;
    __syncthreads();
    mx = fmaxf(fmaxf(redm[0], redm[1]), fmaxf(redm[2], redm[3]));

    float e[8];
    e[0] = __expf(v0.x - mx); e[1] = __expf(v0.y - mx);
    e[2] = __expf(v0.z - mx); e[3] = __expf(v0.w - mx);
    e[4] = __expf(v1.x - mx); e[5] = __expf(v1.y - mx);
    e[6] = __expf(v1.z - mx); e[7] = __expf(v1.w - mx);

    float s = ((e[0] + e[1]) + (e[2] + e[3])) + ((e[4] + e[5]) + (e[6] + e[7]));
#pragma unroll
    for (int o = 32; o >= 1; o >>= 1)
        s += __shfl_xor(s, o, 64);
    if (lane == 0) reds[wid] = s;
    __syncthreads();
    s = (reds[0] + reds[1]) + (reds[2] + reds[3]);

    const float inv = 1.0f / s;
    ((float4*)p)[tid]       = make_float4(e[0] * inv, e[1] * inv, e[2] * inv, e[3] * inv);
    ((float4*)p)[tid + 256] = make_float4(e[4] * inv, e[5] * inv, e[6] * inv, e[7] * inv);
}

extern "C" void kernel_launch(void* const* d_in, const int* in_sizes, int n_in,
                              void* d_out, int out_size, void* d_ws, size_t ws_size,
                              hipStream_t stream)
{
    (void)in_sizes; (void)n_in; (void)out_size; (void)ws_size;

    const float* query = (const float*)d_in[0];  // B,N,H
    const float* value = (const float*)d_in[1];  // B,N,H
    const int*   mask  = (const int*)d_in[2];    // B,N,N
    const float* W     = (const float*)d_in[3];  // H,H

    float* out  = (float*)d_out;                           // B*N*H
    float* attn = out + (size_t)BATCH * SEQ * HID;         // B*N*N

    // workspace: Vp 64MB | Vt 32MB | Wtp 4MB   (assumes ws_size >= 100MB)
    u32* Vp  = (u32*)d_ws;
    u16* Vt  = (u16*)((char*)d_ws + ((size_t)64 << 20));
    u32* Wtp = (u32*)((char*)d_ws + ((size_t)96 << 20));

    // inter (packed hi/lo) staged in the d_out output region: B*N*H u32 = 64MB
    u32* interP = (u32*)d_out;

    prep_v<<<dim3(HID / 64, SEQ / 64, BATCH), 256, 0, stream>>>(value, Vp, Vt);
    prep_w<<<dim3(HID / 64, HID / 64, 1), 256, 0, stream>>>(W, Wtp);

    // gemm1: interP[BN,1024] = split(Q) @ Wtp
    gemm_mfma<1><<<dim3(HID / 128, (BATCH * SEQ) / 128, 1), 256, 0, stream>>>(
        query, Wtp, interP, nullptr,
        BATCH * SEQ, HID, HID, HID, HID, HID, 0, 0, 0, 0);

    // gemm2: logits = relu(interP @ Vp^T) masked -> attn region (fp32)
    gemm_mfma<2><<<dim3(SEQ / 128, SEQ / 128, BATCH), 256, 0, stream>>>(
        interP, Vp, attn, mask,
        SEQ, SEQ, HID, HID, HID, SEQ,
        (long)SEQ * HID, (long)SEQ * HID, (long)SEQ * SEQ, (long)SEQ * SEQ);

    softmax2048<<<dim3(BATCH * SEQ), 256, 0, stream>>>(attn);

    // gemm3: out = attn @ V   (plain f16; B rows from Vt so k=seq contiguous)
    gemm_mfma<3><<<dim3(HID / 128, SEQ / 128, BATCH), 256, 0, stream>>>(
        attn, Vt, out, nullptr,
        SEQ, HID, SEQ, SEQ, SEQ, HID,
        (long)SEQ * SEQ, (long)HID * SEQ, (long)SEQ * HID, 0);
}